// Round 4
// baseline (429.606 us; speedup 1.0000x reference)
//
#include <hip/hip_runtime.h>
#include <hip/hip_bf16.h>

#define E_N 640000
#define N_N 40000

typedef __attribute__((ext_vector_type(8))) short short8;
typedef __attribute__((ext_vector_type(4))) float f32x4;

static __device__ __forceinline__ unsigned short f2bf(float f) {
  __hip_bfloat16 h = __float2bfloat16(f);
  unsigned short u;
  __builtin_memcpy(&u, &h, 2);
  return u;
}
static __device__ __forceinline__ float bf2f(unsigned short u) {
  return __uint_as_float(((unsigned int)u) << 16);
}

// ---------------- Wt[k][o][i] = bf16(W[k][i][o]) ----------------
__global__ __launch_bounds__(256) void wtrans_kernel(
    const float* __restrict__ W, unsigned short* __restrict__ Wt) {
  int t = blockIdx.x * 256 + threadIdx.x;  // 25*64*64 = 102400
  int k = t >> 12, r = t & 4095, o = r >> 6, i = r & 63;
  Wt[(k << 12) | (o << 6) | i] = f2bf(W[(k << 12) | (i << 6) | o]);
}

// ---------------- Y[n,k,o] via MFMA: C[o][node] = Wt_rows x x_cols ----------------
__global__ __launch_bounds__(256) void ygemm_kernel(
    const float* __restrict__ x, const unsigned short* __restrict__ Wt,
    unsigned short* __restrict__ Y) {
  const int n0 = blockIdx.x * 64;
  const int w = threadIdx.x >> 6;
  const int l = threadIdx.x & 63;
  const int lr = l & 15;
  const int lh = l >> 4;

  short8 bx[4][2];
  #pragma unroll
  for (int nt = 0; nt < 4; ++nt) {
    const float* xp = x + ((size_t)(n0 + nt * 16 + lr) << 6) + (lh << 3);
    #pragma unroll
    for (int h = 0; h < 2; ++h) {
      float4 lo = *(const float4*)(xp + h * 32);
      float4 hi = *(const float4*)(xp + h * 32 + 4);
      short8 b;
      b[0] = (short)f2bf(lo.x); b[1] = (short)f2bf(lo.y);
      b[2] = (short)f2bf(lo.z); b[3] = (short)f2bf(lo.w);
      b[4] = (short)f2bf(hi.x); b[5] = (short)f2bf(hi.y);
      b[6] = (short)f2bf(hi.z); b[7] = (short)f2bf(hi.w);
      bx[nt][h] = b;
    }
  }

  const f32x4 Z = {0.0f, 0.0f, 0.0f, 0.0f};

  for (int k = w; k < 25; k += 4) {
    const unsigned short* wk = Wt + ((size_t)k << 12);
    short8 aw[4][2];
    #pragma unroll
    for (int ot = 0; ot < 4; ++ot)
      #pragma unroll
      for (int h = 0; h < 2; ++h)
        aw[ot][h] = *(const short8*)(wk + ((ot * 16 + lr) << 6) + (h << 5) + (lh << 3));

    f32x4 acc[4][4];
    #pragma unroll
    for (int ot = 0; ot < 4; ++ot)
      #pragma unroll
      for (int nt = 0; nt < 4; ++nt) {
        acc[ot][nt] = __builtin_amdgcn_mfma_f32_16x16x32_bf16(aw[ot][0], bx[nt][0], Z, 0, 0, 0);
        acc[ot][nt] = __builtin_amdgcn_mfma_f32_16x16x32_bf16(aw[ot][1], bx[nt][1], acc[ot][nt], 0, 0, 0);
      }

    #pragma unroll
    for (int ot = 0; ot < 4; ++ot)
      #pragma unroll
      for (int nt = 0; nt < 4; ++nt) {
        int node = n0 + nt * 16 + lr;
        int o = ot * 16 + (lh << 2);
        unsigned int p0 = (unsigned)f2bf(acc[ot][nt][0]) | ((unsigned)f2bf(acc[ot][nt][1]) << 16);
        unsigned int p1 = (unsigned)f2bf(acc[ot][nt][2]) | ((unsigned)f2bf(acc[ot][nt][3]) << 16);
        uint2 p; p.x = p0; p.y = p1;
        *(uint2*)(Y + ((size_t)node * 25 + k) * 64 + o) = p;
      }
  }
}

// ---------------- CSR build: histogram -> scan -> scatter ----------------
__global__ __launch_bounds__(256) void hist_kernel(
    const int* __restrict__ ei, int* __restrict__ cnt) {
  int e = blockIdx.x * 256 + threadIdx.x;
  atomicAdd(&cnt[ei[E_N + e]], 1);
}

__global__ __launch_bounds__(256) void scan_kernel(
    const int* __restrict__ cnt, int* __restrict__ start, int* __restrict__ ofs) {
  __shared__ int psum[256];
  const int t = threadIdx.x;
  const int c0 = t * 157;
  const int c1 = (c0 + 157 < N_N) ? c0 + 157 : N_N;
  int s = 0;
  for (int j = c0; j < c1; ++j) s += cnt[j];
  psum[t] = s;
  __syncthreads();
  if (t == 0) {
    int acc = 0;
    for (int i = 0; i < 256; ++i) { int v = psum[i]; psum[i] = acc; acc += v; }
  }
  __syncthreads();
  int run = psum[t];
  for (int j = c0; j < c1; ++j) {
    int c = cnt[j];
    start[j] = run;
    ofs[j] = run;
    run += c;
  }
  if (t == 255) start[N_N] = run;  // == E_N
}

__global__ __launch_bounds__(256) void scatter_kernel(
    const float* __restrict__ ea, const int* __restrict__ ei,
    int* __restrict__ ofs, uint2* __restrict__ recs) {
  int e = blockIdx.x * 256 + threadIdx.x;
  int s = ei[e];
  int d = ei[E_N + e];
  float2 a = ((const float2*)ea)[e];
  float v0 = a.x * 4.0f, v1 = a.y * 4.0f;
  float b0f = fminf(fmaxf(floorf(v0), 0.0f), 3.0f);
  float b1f = fminf(fmaxf(floorf(v1), 0.0f), 3.0f);
  float f0 = v0 - b0f, f1 = v1 - b1f;
  int I0 = (int)b0f * 5 + (int)b1f;
  unsigned int q0 = (unsigned int)(f0 * 65535.0f + 0.5f);
  unsigned int q1 = (unsigned int)(f1 * 65535.0f + 0.5f);
  int pos = atomicAdd(&ofs[d], 1);
  uint2 rc;
  rc.x = (unsigned int)s | ((unsigned int)I0 << 16);
  rc.y = q0 | (q1 << 16);
  recs[pos] = rc;
}

// ---------------- agg (one wave per dst node) + fused root epilogue ----------------
__global__ __launch_bounds__(256) void agg_kernel(
    const unsigned short* __restrict__ Y, const uint2* __restrict__ recs,
    const int* __restrict__ start, const float* __restrict__ xin,
    const float* __restrict__ root, const float* __restrict__ bias,
    float* __restrict__ outp, int relu) {
  __shared__ float xl[4][64];
  const int w = threadIdx.x >> 6;
  const int lane = threadIdx.x & 63;
  const int n = blockIdx.x * 4 + w;
  xl[w][lane] = xin[((size_t)n << 6) + lane];
  __syncthreads();

  const int s = start[n];
  const int e = start[n + 1];
  float acc = -__builtin_inff();
  for (int j = s; j < e; ++j) {
    uint2 rc = recs[j];
    int src = rc.x & 0xffff;
    int I0 = rc.x >> 16;
    float f0 = (float)(rc.y & 0xffff) * (1.0f / 65535.0f);
    float f1 = (float)(rc.y >> 16) * (1.0f / 65535.0f);
    const unsigned short* base = Y + (size_t)src * 1600 + I0 * 64 + lane;
    float y0 = bf2f(base[0]);
    float y1 = bf2f(base[64]);
    float y2 = bf2f(base[320]);
    float y3 = bf2f(base[384]);
    float m = (1.0f - f0) * ((1.0f - f1) * y0 + f1 * y1) +
              f0 * ((1.0f - f1) * y2 + f1 * y3);
    acc = fmaxf(acc, m);
  }
  if (s == e) acc = 0.0f;

  float r = bias[lane];
  #pragma unroll 8
  for (int i = 0; i < 64; ++i)
    r += xl[w][i] * root[(i << 6) + lane];
  r += acc;
  if (relu) r = fmaxf(r, 0.0f);
  outp[((size_t)n << 6) + lane] = r;
}

extern "C" void kernel_launch(void* const* d_in, const int* in_sizes, int n_in,
                              void* d_out, int out_size, void* d_ws, size_t ws_size,
                              hipStream_t stream) {
  const float* x = (const float*)d_in[0];
  const int* ei = (const int*)d_in[1];
  const float* ea = (const float*)d_in[2];
  const float* W1 = (const float*)d_in[3];
  const float* root1 = (const float*)d_in[4];
  const float* bias1 = (const float*)d_in[5];
  const float* W2 = (const float*)d_in[6];
  const float* root2 = (const float*)d_in[7];
  const float* bias2 = (const float*)d_in[8];
  float* out = (float*)d_out;

  const size_t yB = (size_t)N_N * 1600 * 2;   // 128,000,000
  const size_t hB = (size_t)N_N * 64 * 4;     //  10,240,000
  const size_t rB = (size_t)E_N * 8;          //   5,120,000
  const size_t sB = (size_t)(N_N + 1) * 4;    //     160,004
  const size_t oB = (size_t)N_N * 4;          //     160,000
  const size_t cB = (size_t)N_N * 4;          //     160,000
  const size_t wB = (size_t)25 * 64 * 64 * 2; //     204,800
  if (ws_size < yB + hB + rB + sB + oB + cB + wB) return;

  char* p = (char*)d_ws;
  unsigned short* Y = (unsigned short*)p; p += yB;
  float* h = (float*)p;                   p += hB;
  uint2* recs = (uint2*)p;                p += rB;
  int* startA = (int*)p;                  p += sB;
  int* ofs = (int*)p;                     p += oB;
  int* cnt = (int*)p;                     p += cB;
  unsigned short* Wt = (unsigned short*)p;

  dim3 blk(256);

  // ---- CSR build (once, shared by both layers) ----
  hipMemsetAsync(cnt, 0, cB, stream);
  hist_kernel<<<E_N / 256, blk, 0, stream>>>(ei, cnt);
  scan_kernel<<<1, blk, 0, stream>>>(cnt, startA, ofs);
  scatter_kernel<<<E_N / 256, blk, 0, stream>>>(ea, ei, ofs, recs);

  // ---- layer 1 ----
  wtrans_kernel<<<400, blk, 0, stream>>>(W1, Wt);
  ygemm_kernel<<<N_N / 64, blk, 0, stream>>>(x, Wt, Y);
  agg_kernel<<<N_N / 4, blk, 0, stream>>>(Y, recs, startA, x, root1, bias1, h, 1);

  // ---- layer 2 ----
  wtrans_kernel<<<400, blk, 0, stream>>>(W2, Wt);
  ygemm_kernel<<<N_N / 64, blk, 0, stream>>>(h, Wt, Y);
  agg_kernel<<<N_N / 4, blk, 0, stream>>>(Y, recs, startA, h, root2, bias2, out, 0);
}

// Round 5
// 345.732 us; speedup vs baseline: 1.2426x; 1.2426x over previous
//
#include <hip/hip_runtime.h>
#include <hip/hip_bf16.h>

#define E_N 640000
#define N_N 40000
#define SCAN_B 157  // ceil(40000/256)

typedef __attribute__((ext_vector_type(8))) short short8;
typedef __attribute__((ext_vector_type(4))) float f32x4;

static __device__ __forceinline__ unsigned short f2bf(float f) {
  __hip_bfloat16 h = __float2bfloat16(f);
  unsigned short u;
  __builtin_memcpy(&u, &h, 2);
  return u;
}
static __device__ __forceinline__ float bf2f(unsigned short u) {
  return __uint_as_float(((unsigned int)u) << 16);
}

// ---------------- Wt[k][o][i] = bf16(W[k][i][o]) ----------------
__global__ __launch_bounds__(256) void wtrans_kernel(
    const float* __restrict__ W, unsigned short* __restrict__ Wt) {
  int t = blockIdx.x * 256 + threadIdx.x;  // 25*64*64 = 102400
  int k = t >> 12, r = t & 4095, o = r >> 6, i = r & 63;
  Wt[(k << 12) | (o << 6) | i] = f2bf(W[(k << 12) | (i << 6) | o]);
}

// ---------------- Y[n,k,o] via MFMA: C[o][node] = Wt_rows x x_cols ----------------
__global__ __launch_bounds__(256) void ygemm_kernel(
    const float* __restrict__ x, const unsigned short* __restrict__ Wt,
    unsigned short* __restrict__ Y) {
  const int n0 = blockIdx.x * 64;
  const int w = threadIdx.x >> 6;
  const int l = threadIdx.x & 63;
  const int lr = l & 15;
  const int lh = l >> 4;

  short8 bx[4][2];
  #pragma unroll
  for (int nt = 0; nt < 4; ++nt) {
    const float* xp = x + ((size_t)(n0 + nt * 16 + lr) << 6) + (lh << 3);
    #pragma unroll
    for (int h = 0; h < 2; ++h) {
      float4 lo = *(const float4*)(xp + h * 32);
      float4 hi = *(const float4*)(xp + h * 32 + 4);
      short8 b;
      b[0] = (short)f2bf(lo.x); b[1] = (short)f2bf(lo.y);
      b[2] = (short)f2bf(lo.z); b[3] = (short)f2bf(lo.w);
      b[4] = (short)f2bf(hi.x); b[5] = (short)f2bf(hi.y);
      b[6] = (short)f2bf(hi.z); b[7] = (short)f2bf(hi.w);
      bx[nt][h] = b;
    }
  }

  const f32x4 Z = {0.0f, 0.0f, 0.0f, 0.0f};

  for (int k = w; k < 25; k += 4) {
    const unsigned short* wk = Wt + ((size_t)k << 12);
    short8 aw[4][2];
    #pragma unroll
    for (int ot = 0; ot < 4; ++ot)
      #pragma unroll
      for (int h = 0; h < 2; ++h)
        aw[ot][h] = *(const short8*)(wk + ((ot * 16 + lr) << 6) + (h << 5) + (lh << 3));

    f32x4 acc[4][4];
    #pragma unroll
    for (int ot = 0; ot < 4; ++ot)
      #pragma unroll
      for (int nt = 0; nt < 4; ++nt) {
        acc[ot][nt] = __builtin_amdgcn_mfma_f32_16x16x32_bf16(aw[ot][0], bx[nt][0], Z, 0, 0, 0);
        acc[ot][nt] = __builtin_amdgcn_mfma_f32_16x16x32_bf16(aw[ot][1], bx[nt][1], acc[ot][nt], 0, 0, 0);
      }

    #pragma unroll
    for (int ot = 0; ot < 4; ++ot)
      #pragma unroll
      for (int nt = 0; nt < 4; ++nt) {
        int node = n0 + nt * 16 + lr;
        int o = ot * 16 + (lh << 2);
        unsigned int p0 = (unsigned)f2bf(acc[ot][nt][0]) | ((unsigned)f2bf(acc[ot][nt][1]) << 16);
        unsigned int p1 = (unsigned)f2bf(acc[ot][nt][2]) | ((unsigned)f2bf(acc[ot][nt][3]) << 16);
        uint2 p; p.x = p0; p.y = p1;
        *(uint2*)(Y + ((size_t)node * 25 + k) * 64 + o) = p;
      }
  }
}

// ---------------- CSR build: histogram -> 3-stage parallel scan -> scatter ----------------
__global__ __launch_bounds__(256) void hist_kernel(
    const int* __restrict__ ei, int* __restrict__ cnt) {
  int e = blockIdx.x * 256 + threadIdx.x;
  atomicAdd(&cnt[ei[E_N + e]], 1);
}

// stage 1: per-block sum of 256 counts
__global__ __launch_bounds__(256) void scan1_kernel(
    const int* __restrict__ cnt, int* __restrict__ bsum) {
  __shared__ int red[256];
  int t = threadIdx.x;
  int j = blockIdx.x * 256 + t;
  red[t] = (j < N_N) ? cnt[j] : 0;
  __syncthreads();
  #pragma unroll
  for (int s = 128; s > 0; s >>= 1) {
    if (t < s) red[t] += red[t + s];
    __syncthreads();
  }
  if (t == 0) bsum[blockIdx.x] = red[0];
}

// stage 2: exclusive scan of SCAN_B block sums (one block, in LDS)
__global__ __launch_bounds__(256) void scan2_kernel(
    const int* __restrict__ bsum, int* __restrict__ bofs) {
  __shared__ int v[256];
  int t = threadIdx.x;
  v[t] = (t < SCAN_B) ? bsum[t] : 0;
  __syncthreads();
  if (t == 0) {
    int acc = 0;
    for (int i = 0; i < SCAN_B; ++i) { int c = v[i]; v[i] = acc; acc += c; }
  }
  __syncthreads();
  if (t < SCAN_B) bofs[t] = v[t];
}

// stage 3: in-block exclusive scan + block offset -> start, ofs
__global__ __launch_bounds__(256) void scan3_kernel(
    const int* __restrict__ cnt, const int* __restrict__ bofs,
    int* __restrict__ start, int* __restrict__ ofs) {
  __shared__ int v[2][256];
  int t = threadIdx.x;
  int j = blockIdx.x * 256 + t;
  int c = (j < N_N) ? cnt[j] : 0;
  v[0][t] = c;
  __syncthreads();
  int cur = 0;
  #pragma unroll
  for (int s = 1; s < 256; s <<= 1) {  // Hillis-Steele inclusive scan
    v[1 - cur][t] = (t >= s) ? v[cur][t] + v[cur][t - s] : v[cur][t];
    __syncthreads();
    cur = 1 - cur;
  }
  if (j < N_N) {
    int ex = bofs[blockIdx.x] + v[cur][t] - c;  // exclusive
    start[j] = ex;
    ofs[j] = ex;
    if (j == 0) start[N_N] = E_N;  // total is statically known
  }
}

__global__ __launch_bounds__(256) void scatter_kernel(
    const float* __restrict__ ea, const int* __restrict__ ei,
    int* __restrict__ ofs, uint2* __restrict__ recs) {
  int e = blockIdx.x * 256 + threadIdx.x;
  int s = ei[e];
  int d = ei[E_N + e];
  float2 a = ((const float2*)ea)[e];
  float v0 = a.x * 4.0f, v1 = a.y * 4.0f;
  float b0f = fminf(fmaxf(floorf(v0), 0.0f), 3.0f);
  float b1f = fminf(fmaxf(floorf(v1), 0.0f), 3.0f);
  float f0 = v0 - b0f, f1 = v1 - b1f;
  int I0 = (int)b0f * 5 + (int)b1f;
  unsigned int q0 = (unsigned int)(f0 * 65535.0f + 0.5f);
  unsigned int q1 = (unsigned int)(f1 * 65535.0f + 0.5f);
  int pos = atomicAdd(&ofs[d], 1);
  uint2 rc;
  rc.x = (unsigned int)s | ((unsigned int)I0 << 16);
  rc.y = q0 | (q1 << 16);
  recs[pos] = rc;
}

// ---------------- agg (one wave per dst node) + fused root epilogue ----------------
__global__ __launch_bounds__(256) void agg_kernel(
    const unsigned short* __restrict__ Y, const uint2* __restrict__ recs,
    const int* __restrict__ start, const float* __restrict__ xin,
    const float* __restrict__ root, const float* __restrict__ bias,
    float* __restrict__ outp, int relu) {
  __shared__ float xl[4][64];
  const int w = threadIdx.x >> 6;
  const int lane = threadIdx.x & 63;
  const int n = blockIdx.x * 4 + w;
  xl[w][lane] = xin[((size_t)n << 6) + lane];
  __syncthreads();

  const int s = start[n];
  const int e = start[n + 1];
  float acc = -__builtin_inff();
  for (int j = s; j < e; ++j) {
    uint2 rc = recs[j];
    int src = rc.x & 0xffff;
    int I0 = rc.x >> 16;
    float f0 = (float)(rc.y & 0xffff) * (1.0f / 65535.0f);
    float f1 = (float)(rc.y >> 16) * (1.0f / 65535.0f);
    const unsigned short* base = Y + (size_t)src * 1600 + I0 * 64 + lane;
    float y0 = bf2f(base[0]);
    float y1 = bf2f(base[64]);
    float y2 = bf2f(base[320]);
    float y3 = bf2f(base[384]);
    float m = (1.0f - f0) * ((1.0f - f1) * y0 + f1 * y1) +
              f0 * ((1.0f - f1) * y2 + f1 * y3);
    acc = fmaxf(acc, m);
  }
  if (s == e) acc = 0.0f;

  float r = bias[lane];
  #pragma unroll 8
  for (int i = 0; i < 64; ++i)
    r += xl[w][i] * root[(i << 6) + lane];
  r += acc;
  if (relu) r = fmaxf(r, 0.0f);
  outp[((size_t)n << 6) + lane] = r;
}

extern "C" void kernel_launch(void* const* d_in, const int* in_sizes, int n_in,
                              void* d_out, int out_size, void* d_ws, size_t ws_size,
                              hipStream_t stream) {
  const float* x = (const float*)d_in[0];
  const int* ei = (const int*)d_in[1];
  const float* ea = (const float*)d_in[2];
  const float* W1 = (const float*)d_in[3];
  const float* root1 = (const float*)d_in[4];
  const float* bias1 = (const float*)d_in[5];
  const float* W2 = (const float*)d_in[6];
  const float* root2 = (const float*)d_in[7];
  const float* bias2 = (const float*)d_in[8];
  float* out = (float*)d_out;

  const size_t yB = (size_t)N_N * 1600 * 2;   // 128,000,000
  const size_t hB = (size_t)N_N * 64 * 4;     //  10,240,000
  const size_t rB = (size_t)E_N * 8;          //   5,120,000
  const size_t sB = (size_t)(N_N + 1) * 4;    //     160,004
  const size_t oB = (size_t)N_N * 4;
  const size_t cB = (size_t)N_N * 4;
  const size_t wB = (size_t)25 * 64 * 64 * 2; //     204,800
  const size_t bB = (size_t)256 * 4 * 2;
  if (ws_size < yB + hB + rB + sB + oB + cB + wB + bB) return;

  char* p = (char*)d_ws;
  unsigned short* Y = (unsigned short*)p; p += yB;
  float* h = (float*)p;                   p += hB;
  uint2* recs = (uint2*)p;                p += rB;
  int* startA = (int*)p;                  p += sB;
  int* ofs = (int*)p;                     p += oB;
  int* cnt = (int*)p;                     p += cB;
  unsigned short* Wt = (unsigned short*)p; p += wB;
  int* bsum = (int*)p;                    p += 256 * 4;
  int* bofs = (int*)p;

  dim3 blk(256);

  // ---- CSR build (once, shared by both layers) ----
  hipMemsetAsync(cnt, 0, cB, stream);
  hist_kernel<<<E_N / 256, blk, 0, stream>>>(ei, cnt);
  scan1_kernel<<<SCAN_B, blk, 0, stream>>>(cnt, bsum);
  scan2_kernel<<<1, blk, 0, stream>>>(bsum, bofs);
  scan3_kernel<<<SCAN_B, blk, 0, stream>>>(cnt, bofs, startA, ofs);
  scatter_kernel<<<E_N / 256, blk, 0, stream>>>(ea, ei, ofs, recs);

  // ---- layer 1 ----
  wtrans_kernel<<<400, blk, 0, stream>>>(W1, Wt);
  ygemm_kernel<<<N_N / 64, blk, 0, stream>>>(x, Wt, Y);
  agg_kernel<<<N_N / 4, blk, 0, stream>>>(Y, recs, startA, x, root1, bias1, h, 1);

  // ---- layer 2 ----
  wtrans_kernel<<<400, blk, 0, stream>>>(W2, Wt);
  ygemm_kernel<<<N_N / 64, blk, 0, stream>>>(h, Wt, Y);
  agg_kernel<<<N_N / 4, blk, 0, stream>>>(Y, recs, startA, h, root2, bias2, out, 0);
}

// Round 6
// 324.024 us; speedup vs baseline: 1.3258x; 1.0670x over previous
//
#include <hip/hip_runtime.h>
#include <hip/hip_bf16.h>

#define E_N 640000
#define N_N 40000
#define SCAN_B 157  // ceil(40000/256)

typedef __attribute__((ext_vector_type(8))) short short8;
typedef __attribute__((ext_vector_type(4))) float f32x4;

static __device__ __forceinline__ unsigned short f2bf(float f) {
  __hip_bfloat16 h = __float2bfloat16(f);
  unsigned short u;
  __builtin_memcpy(&u, &h, 2);
  return u;
}
static __device__ __forceinline__ float bf2f(unsigned short u) {
  return __uint_as_float(((unsigned int)u) << 16);
}

// ---------------- Wt[k][o][i] = bf16(W[k][i][o]) ----------------
__global__ __launch_bounds__(256) void wtrans_kernel(
    const float* __restrict__ W, unsigned short* __restrict__ Wt) {
  int t = blockIdx.x * 256 + threadIdx.x;  // 25*64*64 = 102400
  int k = t >> 12, r = t & 4095, o = r >> 6, i = r & 63;
  Wt[(k << 12) | (o << 6) | i] = f2bf(W[(k << 12) | (i << 6) | o]);
}

// ---------------- Y[n,k,o] via MFMA: C[o][node] = Wt_rows x x_cols ----------------
__global__ __launch_bounds__(256) void ygemm_kernel(
    const float* __restrict__ x, const unsigned short* __restrict__ Wt,
    unsigned short* __restrict__ Y) {
  const int n0 = blockIdx.x * 64;
  const int w = threadIdx.x >> 6;
  const int l = threadIdx.x & 63;
  const int lr = l & 15;
  const int lh = l >> 4;

  short8 bx[4][2];
  #pragma unroll
  for (int nt = 0; nt < 4; ++nt) {
    const float* xp = x + ((size_t)(n0 + nt * 16 + lr) << 6) + (lh << 3);
    #pragma unroll
    for (int h = 0; h < 2; ++h) {
      float4 lo = *(const float4*)(xp + h * 32);
      float4 hi = *(const float4*)(xp + h * 32 + 4);
      short8 b;
      b[0] = (short)f2bf(lo.x); b[1] = (short)f2bf(lo.y);
      b[2] = (short)f2bf(lo.z); b[3] = (short)f2bf(lo.w);
      b[4] = (short)f2bf(hi.x); b[5] = (short)f2bf(hi.y);
      b[6] = (short)f2bf(hi.z); b[7] = (short)f2bf(hi.w);
      bx[nt][h] = b;
    }
  }

  const f32x4 Z = {0.0f, 0.0f, 0.0f, 0.0f};

  for (int k = w; k < 25; k += 4) {
    const unsigned short* wk = Wt + ((size_t)k << 12);
    short8 aw[4][2];
    #pragma unroll
    for (int ot = 0; ot < 4; ++ot)
      #pragma unroll
      for (int h = 0; h < 2; ++h)
        aw[ot][h] = *(const short8*)(wk + ((ot * 16 + lr) << 6) + (h << 5) + (lh << 3));

    f32x4 acc[4][4];
    #pragma unroll
    for (int ot = 0; ot < 4; ++ot)
      #pragma unroll
      for (int nt = 0; nt < 4; ++nt) {
        acc[ot][nt] = __builtin_amdgcn_mfma_f32_16x16x32_bf16(aw[ot][0], bx[nt][0], Z, 0, 0, 0);
        acc[ot][nt] = __builtin_amdgcn_mfma_f32_16x16x32_bf16(aw[ot][1], bx[nt][1], acc[ot][nt], 0, 0, 0);
      }

    #pragma unroll
    for (int ot = 0; ot < 4; ++ot)
      #pragma unroll
      for (int nt = 0; nt < 4; ++nt) {
        int node = n0 + nt * 16 + lr;
        int o = ot * 16 + (lh << 2);
        unsigned int p0 = (unsigned)f2bf(acc[ot][nt][0]) | ((unsigned)f2bf(acc[ot][nt][1]) << 16);
        unsigned int p1 = (unsigned)f2bf(acc[ot][nt][2]) | ((unsigned)f2bf(acc[ot][nt][3]) << 16);
        uint2 p; p.x = p0; p.y = p1;
        *(uint2*)(Y + ((size_t)node * 25 + k) * 64 + o) = p;
      }
  }
}

// ---------------- CSR build: histogram -> 3-stage parallel scan -> scatter ----------------
__global__ __launch_bounds__(256) void hist_kernel(
    const int* __restrict__ ei, int* __restrict__ cnt) {
  int e = blockIdx.x * 256 + threadIdx.x;
  atomicAdd(&cnt[ei[E_N + e]], 1);
}

__global__ __launch_bounds__(256) void scan1_kernel(
    const int* __restrict__ cnt, int* __restrict__ bsum) {
  __shared__ int red[256];
  int t = threadIdx.x;
  int j = blockIdx.x * 256 + t;
  red[t] = (j < N_N) ? cnt[j] : 0;
  __syncthreads();
  #pragma unroll
  for (int s = 128; s > 0; s >>= 1) {
    if (t < s) red[t] += red[t + s];
    __syncthreads();
  }
  if (t == 0) bsum[blockIdx.x] = red[0];
}

__global__ __launch_bounds__(256) void scan2_kernel(
    const int* __restrict__ bsum, int* __restrict__ bofs) {
  __shared__ int v[256];
  int t = threadIdx.x;
  v[t] = (t < SCAN_B) ? bsum[t] : 0;
  __syncthreads();
  if (t == 0) {
    int acc = 0;
    for (int i = 0; i < SCAN_B; ++i) { int c = v[i]; v[i] = acc; acc += c; }
  }
  __syncthreads();
  if (t < SCAN_B) bofs[t] = v[t];
}

__global__ __launch_bounds__(256) void scan3_kernel(
    const int* __restrict__ cnt, const int* __restrict__ bofs,
    int* __restrict__ start, int* __restrict__ ofs) {
  __shared__ int v[2][256];
  int t = threadIdx.x;
  int j = blockIdx.x * 256 + t;
  int c = (j < N_N) ? cnt[j] : 0;
  v[0][t] = c;
  __syncthreads();
  int cur = 0;
  #pragma unroll
  for (int s = 1; s < 256; s <<= 1) {
    v[1 - cur][t] = (t >= s) ? v[cur][t] + v[cur][t - s] : v[cur][t];
    __syncthreads();
    cur = 1 - cur;
  }
  if (j < N_N) {
    int ex = bofs[blockIdx.x] + v[cur][t] - c;
    start[j] = ex;
    ofs[j] = ex;
    if (j == 0) start[N_N] = E_N;
  }
}

__global__ __launch_bounds__(256) void scatter_kernel(
    const float* __restrict__ ea, const int* __restrict__ ei,
    int* __restrict__ ofs, uint2* __restrict__ recs) {
  int e = blockIdx.x * 256 + threadIdx.x;
  int s = ei[e];
  int d = ei[E_N + e];
  float2 a = ((const float2*)ea)[e];
  float v0 = a.x * 4.0f, v1 = a.y * 4.0f;
  float b0f = fminf(fmaxf(floorf(v0), 0.0f), 3.0f);
  float b1f = fminf(fmaxf(floorf(v1), 0.0f), 3.0f);
  float f0 = v0 - b0f, f1 = v1 - b1f;
  int I0 = (int)b0f * 5 + (int)b1f;
  unsigned int q0 = (unsigned int)(f0 * 65535.0f + 0.5f);
  unsigned int q1 = (unsigned int)(f1 * 65535.0f + 0.5f);
  int pos = atomicAdd(&ofs[d], 1);
  uint2 rc;
  rc.x = (unsigned int)s | ((unsigned int)I0 << 16);
  rc.y = q0 | (q1 << 16);
  recs[pos] = rc;
}

// ---------------- agg (one wave per dst node, 4 indep max chains) + fused epilogue ----------------
static __device__ __forceinline__ float edge_msg(
    const unsigned short* __restrict__ Y, unsigned int rx, unsigned int ry, int lane) {
  int src = rx & 0xffff;
  int I0 = rx >> 16;
  float f0 = (float)(ry & 0xffff) * (1.0f / 65535.0f);
  float f1 = (float)(ry >> 16) * (1.0f / 65535.0f);
  const unsigned short* base = Y + (size_t)src * 1600 + I0 * 64 + lane;
  float y0 = bf2f(base[0]);
  float y1 = bf2f(base[64]);
  float y2 = bf2f(base[320]);
  float y3 = bf2f(base[384]);
  return (1.0f - f0) * ((1.0f - f1) * y0 + f1 * y1) +
         f0 * ((1.0f - f1) * y2 + f1 * y3);
}

__global__ __launch_bounds__(256) void agg_kernel(
    const unsigned short* __restrict__ Y, const uint2* __restrict__ recs,
    const int* __restrict__ start, const float* __restrict__ xin,
    const float* __restrict__ root, const float* __restrict__ bias,
    float* __restrict__ outp, int relu) {
  __shared__ float xl[4][64];
  const int w = threadIdx.x >> 6;
  const int lane = threadIdx.x & 63;
  const int n = blockIdx.x * 4 + w;
  xl[w][lane] = xin[((size_t)n << 6) + lane];
  __syncthreads();

  const int s = start[n];
  const int e = start[n + 1];
  const float NI = -__builtin_inff();
  float a0 = NI, a1 = NI, a2 = NI, a3 = NI;
  int j = s;
  for (; j + 4 <= e; j += 4) {
    uint2 r0 = recs[j];
    uint2 r1 = recs[j + 1];
    uint2 r2 = recs[j + 2];
    uint2 r3 = recs[j + 3];
    float m0 = edge_msg(Y, r0.x, r0.y, lane);
    float m1 = edge_msg(Y, r1.x, r1.y, lane);
    float m2 = edge_msg(Y, r2.x, r2.y, lane);
    float m3 = edge_msg(Y, r3.x, r3.y, lane);
    a0 = fmaxf(a0, m0);
    a1 = fmaxf(a1, m1);
    a2 = fmaxf(a2, m2);
    a3 = fmaxf(a3, m3);
  }
  for (; j < e; ++j) {
    uint2 rc = recs[j];
    a0 = fmaxf(a0, edge_msg(Y, rc.x, rc.y, lane));
  }
  float acc = fmaxf(fmaxf(a0, a1), fmaxf(a2, a3));
  if (s == e) acc = 0.0f;

  float r = bias[lane];
  #pragma unroll 8
  for (int i = 0; i < 64; ++i)
    r += xl[w][i] * root[(i << 6) + lane];
  r += acc;
  if (relu) r = fmaxf(r, 0.0f);
  outp[((size_t)n << 6) + lane] = r;
}

extern "C" void kernel_launch(void* const* d_in, const int* in_sizes, int n_in,
                              void* d_out, int out_size, void* d_ws, size_t ws_size,
                              hipStream_t stream) {
  const float* x = (const float*)d_in[0];
  const int* ei = (const int*)d_in[1];
  const float* ea = (const float*)d_in[2];
  const float* W1 = (const float*)d_in[3];
  const float* root1 = (const float*)d_in[4];
  const float* bias1 = (const float*)d_in[5];
  const float* W2 = (const float*)d_in[6];
  const float* root2 = (const float*)d_in[7];
  const float* bias2 = (const float*)d_in[8];
  float* out = (float*)d_out;

  const size_t yB = (size_t)N_N * 1600 * 2;   // 128,000,000
  const size_t hB = (size_t)N_N * 64 * 4;     //  10,240,000
  const size_t rB = (size_t)E_N * 8;          //   5,120,000
  const size_t sB = (size_t)(N_N + 1) * 4;
  const size_t oB = (size_t)N_N * 4;
  const size_t cB = (size_t)N_N * 4;
  const size_t wB = (size_t)25 * 64 * 64 * 2; //     204,800
  const size_t bB = (size_t)256 * 4 * 2;
  if (ws_size < yB + hB + rB + sB + oB + cB + wB + bB) return;

  char* p = (char*)d_ws;
  unsigned short* Y = (unsigned short*)p; p += yB;
  float* h = (float*)p;                   p += hB;
  uint2* recs = (uint2*)p;                p += rB;
  int* startA = (int*)p;                  p += sB;
  int* ofs = (int*)p;                     p += oB;
  int* cnt = (int*)p;                     p += cB;
  unsigned short* Wt = (unsigned short*)p; p += wB;
  int* bsum = (int*)p;                    p += 256 * 4;
  int* bofs = (int*)p;

  dim3 blk(256);

  // ---- CSR build (once, shared by both layers) ----
  hipMemsetAsync(cnt, 0, cB, stream);
  hist_kernel<<<E_N / 256, blk, 0, stream>>>(ei, cnt);
  scan1_kernel<<<SCAN_B, blk, 0, stream>>>(cnt, bsum);
  scan2_kernel<<<1, blk, 0, stream>>>(bsum, bofs);
  scan3_kernel<<<SCAN_B, blk, 0, stream>>>(cnt, bofs, startA, ofs);
  scatter_kernel<<<E_N / 256, blk, 0, stream>>>(ea, ei, ofs, recs);

  // ---- layer 1 ----
  wtrans_kernel<<<400, blk, 0, stream>>>(W1, Wt);
  ygemm_kernel<<<N_N / 64, blk, 0, stream>>>(x, Wt, Y);
  agg_kernel<<<N_N / 4, blk, 0, stream>>>(Y, recs, startA, x, root1, bias1, h, 1);

  // ---- layer 2 ----
  wtrans_kernel<<<400, blk, 0, stream>>>(W2, Wt);
  ygemm_kernel<<<N_N / 64, blk, 0, stream>>>(h, Wt, Y);
  agg_kernel<<<N_N / 4, blk, 0, stream>>>(Y, recs, startA, h, root2, bias2, out, 0);
}